// Round 1
// baseline (365.200 us; speedup 1.0000x reference)
//
#include <hip/hip_runtime.h>

typedef float f32x4 __attribute__((ext_vector_type(4)));
typedef float f32x16 __attribute__((ext_vector_type(16)));
typedef __bf16 bf16x8 __attribute__((ext_vector_type(8)));

__device__ __forceinline__ unsigned short f2bf(float f) {
  unsigned int u = __float_as_uint(f);
  u = (u + 0x7FFFu + ((u >> 16) & 1u)) >> 16;
  return (unsigned short)u;
}

__device__ __forceinline__ f32x4 mfma16(bf16x8 a, bf16x8 b, f32x4 c) {
  return __builtin_amdgcn_mfma_f32_16x16x32_bf16(a, b, c, 0, 0, 0);
}
__device__ __forceinline__ f32x16 mfma32(bf16x8 a, bf16x8 b, f32x16 c) {
  return __builtin_amdgcn_mfma_f32_32x32x16_bf16(a, b, c, 0, 0, 0);
}

// packed f32->bf16 pair (RNE), lo = a, hi = b
__device__ __forceinline__ unsigned int cvtpk_bf16(float a, float b) {
  unsigned int r;
  asm("v_cvt_pk_bf16_f32 %0, %1, %2" : "=v"(r) : "v"(a), "v"(b));
  return r;
}
// swap upper 32 lanes of a with lower 32 lanes of b (both outputs used)
__device__ __forceinline__ void pl32swap(unsigned int& a, unsigned int& b) {
  asm("v_permlane32_swap_b32 %0, %1" : "+v"(a), "+v"(b));
}

__device__ __forceinline__ void load8_bf16(const unsigned short* p, unsigned short* d) {
  *(uint4*)d = *(const uint4*)p;
}
__device__ __forceinline__ void load8_bf16(const float* p, unsigned short* d) {
  float4 a = *(const float4*)p;
  float4 b = *(const float4*)(p + 4);
  __align__(16) unsigned short t[8] = {f2bf(a.x), f2bf(a.y), f2bf(a.z), f2bf(a.w),
                                       f2bf(b.x), f2bf(b.y), f2bf(b.z), f2bf(b.w)};
  *(uint4*)d = *(uint4*)t;
}

// Async global->LDS 16B DMA. LDS dest must be wave-uniform base + lane*16
// (our staging maps are exactly lane-linear per wave).
__device__ __forceinline__ void gload_lds16(const unsigned short* g, unsigned short* l) {
  __builtin_amdgcn_global_load_lds(
      (const __attribute__((address_space(1))) void*)g,
      (__attribute__((address_space(3))) void*)l, 16, 0, 0);
}

// fp32 -> bf16, 8 elems/thread.
__global__ __launch_bounds__(256) void convert_gen(const float* __restrict__ src,
                                                   unsigned short* __restrict__ dst) {
  int idx = (blockIdx.x * 256 + threadIdx.x) * 8;
  __align__(16) unsigned short t[8];
  load8_bf16(src + idx, t);
  *(uint4*)(dst + idx) = *(uint4*)t;
}

// W1|W2|W3 (each 1M fp32) -> contiguous bf16. 1536 blocks.
__global__ __launch_bounds__(256) void convert_w3(const float* __restrict__ W1,
                                                  const float* __restrict__ W2,
                                                  const float* __restrict__ W3,
                                                  unsigned short* __restrict__ dst) {
  int i = blockIdx.x;
  int sel = i >> 9;
  const float* src = (sel == 0) ? W1 : (sel == 1) ? W2 : W3;
  int off = (i & 511) * 2048 + threadIdx.x * 8;
  __align__(16) unsigned short t[8];
  load8_bf16(src + off, t);
  *(uint4*)(dst + sel * 1048576 + off) = *(uint4*)t;
}

// Fused QKV projection, all-bf16, global_load_lds staging, unpadded LDS.
// blockIdx.x in [0,24): sel = x>>3 (0:q,1:k,2:v), nb=(x&7)*128.
__global__ __launch_bounds__(256) void gemm_qkv(const unsigned short* __restrict__ A,
                                                const unsigned short* __restrict__ WB,
                                                unsigned short* __restrict__ q,
                                                unsigned short* __restrict__ k,
                                                unsigned short* __restrict__ v) {
  __shared__ __align__(16) unsigned short As[128][32];  // unpadded: lane-linear staging,
  __shared__ __align__(16) unsigned short Bs[128][32];  // b128 reads granule-uniform
  const int t = threadIdx.x;
  const int lane = t & 63;
  const int wid = t >> 6;
  const int quad = lane >> 4;
  const int l16 = lane & 15;
  const int wm = (wid >> 1) << 6;
  const int wn = (wid & 1) << 6;
  const int sel = blockIdx.x >> 3;
  const int nb = (blockIdx.x & 7) << 7;
  const int mbase = blockIdx.y * 128;
  const unsigned short* Bt = WB + sel * 1048576;
  unsigned short* C = (sel == 0) ? q : (sel == 1) ? k : v;

  f32x4 acc[4][4] = {};

  for (int k0 = 0; k0 < 1024; k0 += 32) {
#pragma unroll
    for (int i = 0; i < 2; ++i) {
      int c = t + (i << 8);
      int row = c >> 2;
      int col = (c & 3) << 3;
      gload_lds16(A + (size_t)(mbase + row) * 1024 + k0 + col, &As[row][col]);
      gload_lds16(Bt + (size_t)(nb + row) * 1024 + k0 + col, &Bs[row][col]);
    }
    __syncthreads();
    bf16x8 af[4], bfr[4];
#pragma unroll
    for (int mt = 0; mt < 4; ++mt)
      af[mt] = *(const bf16x8*)(&As[wm + mt * 16 + l16][quad * 8]);
#pragma unroll
    for (int nt = 0; nt < 4; ++nt)
      bfr[nt] = *(const bf16x8*)(&Bs[wn + nt * 16 + l16][quad * 8]);
#pragma unroll
    for (int mt = 0; mt < 4; ++mt)
#pragma unroll
      for (int nt = 0; nt < 4; ++nt)
        acc[mt][nt] = mfma16(af[mt], bfr[nt], acc[mt][nt]);
    __syncthreads();
  }

  const bool rope = (sel < 2);
#pragma unroll
  for (int mt = 0; mt < 4; ++mt) {
#pragma unroll
    for (int nt = 0; nt < 4; ++nt) {
#pragma unroll
      for (int r = 0; r < 4; ++r) {
        int row_g = mbase + wm + mt * 16 + quad * 4 + r;
        int col_g = nb + wn + nt * 16 + l16;
        float val = acc[mt][nt][r];
        if (rope) {  // interleaved RoPE; partner col = col^1 lives in lane^1
          float other = __shfl_xor(val, 1);
          int s = (((row_g & 2047) << 3) + (col_g >> 7)) & 2047;  // view-seq position
          int d = col_g & 127;
          float invf = __expf(-0.14391156f * (float)(d >> 1));  // ln(1e4)/64
          float ang = (float)s * invf;
          float sv, cv;
          __sincosf(ang, &sv, &cv);
          val = (d & 1) ? (val * cv + other * sv) : (val * cv - other * sv);
        }
        C[(size_t)row_g * 1024 + col_g] = f2bf(val);
      }
    }
  }
}

// Plain per-bh transpose: vT[bh][d][s] = v[bh][s][d].
__global__ __launch_bounds__(256) void transpose_v(const unsigned short* __restrict__ Vn,
                                                   unsigned short* __restrict__ VT) {
  __shared__ __align__(16) unsigned short tile[64][72];
  const int t = threadIdx.x;
  const int s0 = blockIdx.x * 64;
  const int d0 = blockIdx.y * 64;
  const int bh = blockIdx.z;
  const size_t base = (size_t)bh * (2048 * 128);
#pragma unroll
  for (int i = 0; i < 2; ++i) {
    int c = t + (i << 8);
    int sr = c >> 3;
    int dc = (c & 7) << 3;
    *(uint4*)(&tile[sr][dc]) = *(const uint4*)(Vn + base + (size_t)(s0 + sr) * 128 + d0 + dc);
  }
  __syncthreads();
#pragma unroll
  for (int i = 0; i < 2; ++i) {
    int c = t + (i << 8);
    int dr = c >> 3;
    int sc = (c & 7) << 3;
    __align__(16) unsigned short tmp[8];
#pragma unroll
    for (int j = 0; j < 8; ++j) tmp[j] = tile[sc + j][dr];
    *(uint4*)(VT + base + (size_t)(d0 + dr) * 2048 + s0 + sc) = *(uint4*)tmp;
  }
}

// Final projection: A rows remap RowLinear pre-shuffle onto oT[bh][d][s];
// global_load_lds staging; output-permutation fp32 store (LDS transposed, coalesced).
__global__ __launch_bounds__(256) void gemm_out(const unsigned short* __restrict__ OT,
                                                const unsigned short* __restrict__ Bt,
                                                float* __restrict__ C) {
  __shared__ __align__(16) char smem_raw[128 * 68 * 4];  // Ts epilogue needs 34816 B
  auto As = (unsigned short(*)[32])smem_raw;
  auto Bs = (unsigned short(*)[32])(smem_raw + 128 * 32 * 2);
  const int t = threadIdx.x;
  const int lane = t & 63;
  const int wid = t >> 6;
  const int quad = lane >> 4;
  const int l16 = lane & 15;
  const int wm = (wid >> 1) << 6;
  const int wn = (wid & 1) << 6;
  const int mbase = blockIdx.y * 128;
  const int nbase = blockIdx.x * 128;

  f32x4 acc[4][4] = {};

  for (int k0 = 0; k0 < 1024; k0 += 32) {
#pragma unroll
    for (int i = 0; i < 2; ++i) {
      int c = t + (i << 8);
      int row = c >> 2;
      int col = (c & 3) << 3;
      int R = mbase + row;
      int b = R >> 11;
      int ii = R & 2047;
      const unsigned short* src = OT + (size_t)(b * 8 + (ii >> 8)) * (128 * 2048) +
                                  (size_t)((ii >> 1) & 127) * 2048 + ((ii & 1) << 10) +
                                  k0 + col;
      gload_lds16(src, &As[row][col]);
      gload_lds16(Bt + (size_t)(nbase + row) * 1024 + k0 + col, &Bs[row][col]);
    }
    __syncthreads();
    bf16x8 af[4], bfr[4];
#pragma unroll
    for (int mt = 0; mt < 4; ++mt)
      af[mt] = *(const bf16x8*)(&As[wm + mt * 16 + l16][quad * 8]);
#pragma unroll
    for (int nt = 0; nt < 4; ++nt)
      bfr[nt] = *(const bf16x8*)(&Bs[wn + nt * 16 + l16][quad * 8]);
#pragma unroll
    for (int mt = 0; mt < 4; ++mt)
#pragma unroll
      for (int nt = 0; nt < 4; ++nt)
        acc[mt][nt] = mfma16(af[mt], bfr[nt], acc[mt][nt]);
    __syncthreads();
  }

  // out[b][s2][e2], s2 = (row&1)*1024 + col, e2 = (row&2047)>>1.
  float(*Ts)[68] = (float(*)[68])smem_raw;
  const int b = mbase >> 11;
  const int ebase = (mbase & 2047) >> 1;
#pragma unroll
  for (int p = 0; p < 2; ++p) {
    __syncthreads();
#pragma unroll
    for (int mt = 0; mt < 4; ++mt)
#pragma unroll
      for (int nt = 0; nt < 4; ++nt)
#pragma unroll
        for (int rr = p; rr < 4; rr += 2) {
          int col_local = wn + nt * 16 + l16;
          int row_local = wm + mt * 16 + quad * 4 + rr;
          Ts[col_local][row_local >> 1] = acc[mt][nt][rr];
        }
    __syncthreads();
    int srow = t >> 1;
    int e0 = (t & 1) << 5;
    float* dst = C + (size_t)b * 2097152 +
                 (size_t)(p * 1024 + nbase + srow) * 1024 + ebase + e0;
#pragma unroll
    for (int j = 0; j < 8; ++j)
      ((float4*)dst)[j] = *(const float4*)&Ts[srow][e0 + j * 4];
  }
}

// Flash attention [BH=32, S=2048, D=128]; BQ=128 (4 waves x 32 q-cols), BKV=64.
// Swapped QK^T on 32x32 MFMA: S^T in regs (q = lane&31), in-register softmax
// (per-lane m/l, one shfl_xor(32) per reduce), cvt_pk+permlane32_swap P-repack,
// PV as V^T x P^T -> O^T directly. K/V LDS XOR-chunk-swizzled, double-buffered.
__global__ __launch_bounds__(256, 2) void flash_attn(const unsigned short* __restrict__ Q,
                                                     const unsigned short* __restrict__ Kg,
                                                     const unsigned short* __restrict__ VTg,
                                                     unsigned short* __restrict__ OT) {
  __shared__ __align__(16) char sm[65536];  // 2 x (K 16KB + V 16KB); epilogue reuses 34816B
  const int t = threadIdx.x;
  const int lane = t & 63;
  const int wid = t >> 6;
  const int l31 = lane & 31;
  const int hi = lane >> 5;
  const int x16 = (l31 & 7) << 4;  // XOR swizzle key (byte units)
  const int i = blockIdx.x;                 // [0,512); XCD-aware swizzle
  const int bh = (i & 7) + ((i >> 3) & 3) * 8;
  const int qbase = (i >> 5) << 7;
  const size_t base = (size_t)bh * (2048 * 128);
  const float scale = 0.3535533905932738f;  // 1/sqrt(H=8)

  // Q fragments (B-operand): j = q = l31, k-dim slice = hi*8 within each 16.
  bf16x8 qf[8];
  {
    const unsigned short* qp = Q + base + (size_t)(qbase + wid * 32 + l31) * 128 + hi * 8;
#pragma unroll
    for (int ks = 0; ks < 8; ++ks) qf[ks] = *(const bf16x8*)(qp + ks * 16);
  }

  f32x16 accO[4] = {};  // O^T: rows d (dt*32 + ...), cols q = l31
  float m = -__builtin_inff();
  float l = 0.f;

  uint4 kreg[4], vreg[4];
  const unsigned short* Kg_b = Kg + base;
  const unsigned short* Vg_b = VTg + base;

  // prologue: stage tile 0 into buffer 0
#pragma unroll
  for (int j = 0; j < 4; ++j) {
    int c = t + (j << 8);
    kreg[j] = *(const uint4*)(Kg_b + (size_t)(c >> 4) * 128 + ((c & 15) << 3));
    vreg[j] = *(const uint4*)(Vg_b + (size_t)(c >> 3) * 2048 + ((c & 7) << 3));
  }
  {
    unsigned short* Kw = (unsigned short*)sm;
    unsigned short* Vw = (unsigned short*)(sm + 16384);
#pragma unroll
    for (int j = 0; j < 4; ++j) {
      int c = t + (j << 8);
      int r = c >> 4, ch = c & 15;
      *(uint4*)(Kw + r * 128 + ((ch ^ (r & 7)) << 3)) = kreg[j];
      int d = c >> 3, cv = c & 7;
      *(uint4*)(Vw + d * 64 + ((cv ^ (d & 7)) << 3)) = vreg[j];
    }
  }
  __syncthreads();

  int cur = 0;
  for (int kv = 0; kv < 2048; kv += 64) {
    const bool nxt = (kv + 64) < 2048;
    if (nxt) {  // issue next-tile global loads early (hide under compute)
#pragma unroll
      for (int j = 0; j < 4; ++j) {
        int c = t + (j << 8);
        kreg[j] = *(const uint4*)(Kg_b + (size_t)(kv + 64 + (c >> 4)) * 128 + ((c & 15) << 3));
        vreg[j] = *(const uint4*)(Vg_b + (size_t)(c >> 3) * 2048 + (kv + 64) + ((c & 7) << 3));
      }
    }
    const char* Kb = sm + (cur << 15);
    const char* Vb = Kb + 16384;

    // QK^T swapped: accS[nt] = S^T (rows k = nt*32+..., cols q = l31)
    f32x16 s0 = {}, s1 = {};
#pragma unroll
    for (int ks = 0; ks < 8; ++ks) {
      int cb = (ks * 32 + hi * 16) ^ x16;
      bf16x8 k0 = *(const bf16x8*)(Kb + l31 * 256 + cb);
      bf16x8 k1 = *(const bf16x8*)(Kb + 8192 + l31 * 256 + cb);
      s0 = mfma32(k0, qf[ks], s0);
      s1 = mfma32(k1, qf[ks], s1);
    }

    // online softmax: per-lane row (q = l31), 32 values + partner half
    float mx = s0[0];
#pragma unroll
    for (int r = 1; r < 16; ++r) mx = fmaxf(mx, s0[r]);
#pragma unroll
    for (int r = 0; r < 16; ++r) mx = fmaxf(mx, s1[r]);
    mx = fmaxf(mx, __shfl_xor(mx, 32));
    if (__any(mx > m + 16.f)) {  // defer-max: P bounded by e^(16*scale)=287
      float mnew = fmaxf(m, mx);
      float alpha = __expf((m - mnew) * scale);
      l *= alpha;
#pragma unroll
      for (int dt = 0; dt < 4; ++dt)
#pragma unroll
        for (int r = 0; r < 16; ++r) accO[dt][r] *= alpha;
      m = mnew;
    }
    float negms = -m * scale;
    float ps = 0.f;
#pragma unroll
    for (int r = 0; r < 16; ++r) {
      s0[r] = __expf(fmaf(s0[r], scale, negms));
      ps += s0[r];
    }
#pragma unroll
    for (int r = 0; r < 16; ++r) {
      s1[r] = __expf(fmaf(s1[r], scale, negms));
      ps += s1[r];
    }
    ps += __shfl_xor(ps, 32);
    l += ps;

    // repack P^T -> B-fragments (k-blocks of 16): cvt_pk pairs + permlane32_swap.
    // C-layout rows per lane: (r&3)+8*(r>>2)+4*hi  => swap(pk0,pk2)/(pk1,pk3)
    // yields words (w0,w2)/(w1,w3) of the B-frag for ALL lanes.
    bf16x8 pfrag[4];
#pragma unroll
    for (int kb = 0; kb < 4; ++kb) {
      const f32x16& S = (kb < 2) ? s0 : s1;
      const int b = (kb & 1) * 8;
      unsigned int a0 = cvtpk_bf16(S[b + 0], S[b + 1]);
      unsigned int a1 = cvtpk_bf16(S[b + 2], S[b + 3]);
      unsigned int a2 = cvtpk_bf16(S[b + 4], S[b + 5]);
      unsigned int a3 = cvtpk_bf16(S[b + 6], S[b + 7]);
      pl32swap(a0, a2);
      pl32swap(a1, a3);
      union { unsigned int u[4]; bf16x8 v; } pu;
      pu.u[0] = a0; pu.u[1] = a1; pu.u[2] = a2; pu.u[3] = a3;
      pfrag[kb] = pu.v;
    }

    // PV: O^T[d][q] += V^T-frag (i=d) x P^T-frag (j=q)
#pragma unroll
    for (int dt = 0; dt < 4; ++dt) {
#pragma unroll
      for (int kb = 0; kb < 4; ++kb) {
        bf16x8 vfr = *(const bf16x8*)(Vb + l31 * 128 + dt * 4096 + ((kb * 32 + hi * 16) ^ x16));
        accO[dt] = mfma32(vfr, pfrag[kb], accO[dt]);
      }
    }

    if (nxt) {  // write next tile into the other buffer
      unsigned short* Kw = (unsigned short*)(sm + ((cur ^ 1) << 15));
      unsigned short* Vw = (unsigned short*)((char*)Kw + 16384);
#pragma unroll
      for (int j = 0; j < 4; ++j) {
        int c = t + (j << 8);
        int r = c >> 4, ch = c & 15;
        *(uint4*)(Kw + r * 128 + ((ch ^ (r & 7)) << 3)) = kreg[j];
        int d = c >> 3, cv = c & 7;
        *(uint4*)(Vw + d * 64 + ((cv ^ (d & 7)) << 3)) = vreg[j];
      }
    }
    __syncthreads();
    cur ^= 1;
  }

  // epilogue: accO is already O^T; normalize and stage to LDS for coalesced store
  auto To = (unsigned short(*)[136])sm;
  const float invl = 1.f / l;
  const int qloc = wid * 32 + l31;
#pragma unroll
  for (int dt = 0; dt < 4; ++dt)
#pragma unroll
    for (int r = 0; r < 16; ++r) {
      int d = dt * 32 + (r & 3) + ((r >> 2) << 3) + hi * 4;
      To[d][qloc] = f2bf(accO[dt][r] * invl);
    }
  __syncthreads();
  int dr = t >> 1;
  int off = (t & 1) << 6;
  unsigned short* dst = OT + base + (size_t)dr * 2048 + qbase + off;
#pragma unroll
  for (int j = 0; j < 8; ++j)
    ((uint4*)dst)[j] = *(const uint4*)&To[dr][off + j * 8];
}

extern "C" void kernel_launch(void* const* d_in, const int* in_sizes, int n_in,
                              void* d_out, int out_size, void* d_ws, size_t ws_size,
                              hipStream_t stream) {
  const float* emb = (const float*)d_in[0];
  const float* W1  = (const float*)d_in[1];
  const float* W2  = (const float*)d_in[2];
  const float* W3  = (const float*)d_in[3];
  const float* Wo  = (const float*)d_in[4];
  float* out = (float*)d_out;

  const size_t NELEM = (size_t)8 * 1024 * 1024;  // bf16 elems per [B*S, P] buffer
  unsigned short* q     = (unsigned short*)d_ws;   // [0,16) MB
  unsigned short* k     = q + NELEM;               // [16,32)
  unsigned short* vn    = k + NELEM;               // [32,48); later oT
  unsigned short* X     = vn + NELEM;              // [48,64): W123B -> vT -> WoB
  unsigned short* oT    = vn;
  unsigned short* vT    = X;
  unsigned short* W123B = X;                       // 6 MB, dead before vT written
  unsigned short* WoB   = X;                       // 2 MB, written after flash
  unsigned short* embB  = (unsigned short*)d_out;  // 16 MB bf16 scratch in the 32 MB
                                                   // fp32 out buffer; overwritten by gemm_out

  dim3 blk(256, 1, 1);
  convert_w3<<<dim3(1536), blk, 0, stream>>>(W1, W2, W3, W123B);
  convert_gen<<<dim3(4096), blk, 0, stream>>>(emb, embB);
  gemm_qkv<<<dim3(24, 64), blk, 0, stream>>>(embB, W123B, q, k, vn);
  transpose_v<<<dim3(32, 2, 32), blk, 0, stream>>>(vn, vT);
  flash_attn<<<dim3(512, 1, 1), blk, 0, stream>>>(q, k, vT, oT);
  convert_gen<<<dim3(512), blk, 0, stream>>>(Wo, WoB);
  gemm_out<<<dim3(8, 64), blk, 0, stream>>>(oT, WoB, out);
}